// Round 12
// baseline (90.203 us; speedup 1.0000x reference)
//
#include <hip/hip_runtime.h>

#define FD 768
#define HD 256
#define NF 512
#define NC 512
#define PAIRS (NF * (NF - 1) / 2)   // 130816

typedef __attribute__((ext_vector_type(4))) float f32x4;
typedef __attribute__((ext_vector_type(8))) short bf16x8;

// RNE float->bf16, packed pair (a = low 16, b = high 16)
__device__ inline unsigned bf16pk(float a, float b) {
    unsigned ua = __float_as_uint(a), ub = __float_as_uint(b);
    ua = (ua + 0x7FFFu + ((ua >> 16) & 1u)) >> 16;
    ub = (ub + 0x7FFFu + ((ub >> 16) & 1u)) >> 16;
    return ua | (ub << 16);
}

// ---------------------------------------------------------------------------
// Kernel 1 (EXACT R10 code — validated twice, absmax 0.0156):
// C = E @ [W1top|W1bot] + [b1|0], bf16 MFMA, f32 accum. Grid 16x16, 32x32
// tile, 4 waves, K=768 in 3 rounds of 256. Coalesced f4 staging; XOR LDS.
// D layout: lane l, reg p -> C[r0+16wr+(l&15)][c0+16wc+4(l>>4)+p]
// ---------------------------------------------------------------------------
__global__ __launch_bounds__(256) void gemm_mfma_kernel(
    const float* __restrict__ E, const float* __restrict__ W1,
    const float* __restrict__ b1, float* __restrict__ C)
{
    __shared__ char lds[2 * 32 * 512];          // Et 16KB + Wt 16KB
    char* EtB = lds;
    char* WtB = lds + 32 * 512;

    const int tid  = threadIdx.x;
    const int r0   = blockIdx.y * 32, c0 = blockIdx.x * 32;
    const int c0w4 = (c0 & 255) >> 2;           // f4 col offset within W half
    const int dofs = (c0 >= 256) ? FD : 0;
    const int lane = tid & 63, wave = tid >> 6;
    const int wr = wave >> 1, wc = wave & 1;
    const int m = lane & 15, g = lane >> 4;
    const int arow = 16 * wc + m;               // Wt row (= local C col)
    const int brow = 16 * wr + m;               // Et row (= local C row)

    f32x4 acc = {0.f, 0.f, 0.f, 0.f};
    const float4* E4  = (const float4*)E;       // row pitch 192 f4
    const float4* W14 = (const float4*)W1;      // row pitch 64 f4

    for (int rnd = 0; rnd < 3; ++rnd) {
        if (rnd) __syncthreads();               // LDS reuse guard

        // ---- stage Et: 32 rows x 256 k, f4 loads + packed b64 writes ----
        #pragma unroll
        for (int s = 0; s < 8; ++s) {
            int idx = tid + s * 256;            // 2048 f4
            int r = idx >> 6, c4 = idx & 63;    // k = 4*c4
            float4 v = E4[(size_t)(r0 + r) * 192 + rnd * 64 + c4];
            uint2 pk;
            pk.x = bf16pk(v.x, v.y);
            pk.y = bf16pk(v.z, v.w);
            int gi = (c4 >> 1) ^ (r & 7);
            *(uint2*)(EtB + r * 512 + gi * 16 + (c4 & 1) * 8) = pk;
        }
        // ---- stage Wt: coalesced f4 loads + b32 scatter ----
        #pragma unroll
        for (int it2 = 0; it2 < 4; ++it2) {
            int task = it2 * 256 + tid;         // 1024 = 8 c-quads x 128 kp
            int c4 = task & 7, kp = task >> 3;
            int d = dofs + rnd * 256 + 2 * kp;
            float4 w0 = W14[(size_t)d * 64 + c0w4 + c4];
            float4 w1 = W14[(size_t)(d + 1) * 64 + c0w4 + c4];
            float a0v[4] = {w0.x, w0.y, w0.z, w0.w};
            float a1v[4] = {w1.x, w1.y, w1.z, w1.w};
            #pragma unroll
            for (int u = 0; u < 4; ++u) {
                int c = 4 * c4 + u;
                unsigned pk = bf16pk(a0v[u], a1v[u]);
                int gi = (kp >> 2) ^ (c & 7);
                *(unsigned*)(WtB + c * 512 + gi * 16 + (kp & 3) * 4) = pk;
            }
        }
        __syncthreads();

        // ---- 8 mfma per wave (K chunk = 256) ----
        #pragma unroll
        for (int ks = 0; ks < 8; ++ks) {
            int giA = (4 * ks + g) ^ (arow & 7);
            int giB = (4 * ks + g) ^ (brow & 7);
            bf16x8 af = *(const bf16x8*)(WtB + arow * 512 + giA * 16);
            bf16x8 bf = *(const bf16x8*)(EtB + brow * 512 + giB * 16);
            acc = __builtin_amdgcn_mfma_f32_16x16x32_bf16(af, bf, acc, 0, 0, 0);
        }
    }

    const int row = r0 + 16 * wr + m;           // n = l&15
    const int col = c0 + 16 * wc + 4 * g;       // m = 4*(l>>4)+p
    float4 b = {0.f, 0.f, 0.f, 0.f};
    if (c0 < 256) b = ((const float4*)b1)[col >> 2];
    float4 o = {acc[0] + b.x, acc[1] + b.y, acc[2] + b.z, acc[3] + b.w};
    *(float4*)&C[(size_t)row * NC + col] = o;
}

// ---------------------------------------------------------------------------
// Kernel 2: pair scores. 16x32 tile, 272 blocks, 256 thr, 1x2 micro — same
// structure/numerics as R10 (bitwise-identical accumulation), with A moved
// OFF the LDS pipe: A-row f4s loaded from global C (broadcast across 16
// tx-lanes, 4 rows/wave, L1-friendly) in chunks of 8; only B staged in LDS
// (2 ds_read_b128 per k4 instead of 3; As staging deleted).
// ---------------------------------------------------------------------------
__global__ __launch_bounds__(256) void pair_kernel(
    const float* __restrict__ C, const float* __restrict__ W2,
    const float* __restrict__ b2, float* __restrict__ out)
{
    __shared__ float4 Bs[32 * 64];

    int rem = blockIdx.x, bi = 0;
    while (rem >= 16 - (bi >> 1)) { rem -= 16 - (bi >> 1); ++bi; }
    const int bj = (bi >> 1) + rem;
    const int i0 = bi * 16, j0 = bj * 32;

    const int tid = threadIdx.x;
    const float4* C4 = (const float4*)C;        // row pitch 128 f4

    #pragma unroll
    for (int s = 0; s < 8; ++s) {               // B: 32 rows x 64 f4
        int idx = tid + 256 * s;
        int row = idx >> 6, c4 = idx & 63;
        Bs[row * 64 + (c4 ^ ((row >> 1) & 7))] = C4[(j0 + row) * 128 + 64 + c4];
    }
    __syncthreads();

    const int tx = tid & 15, ty = tid >> 4;
    const int keyB = tx & 7;
    const float4* W24  = (const float4*)W2;     // uniform -> s_load
    const float4* Arow = &C4[(size_t)(i0 + ty) * 128];  // A half of row i

    float acc0 = 0.f, acc1 = 0.f;
    #pragma unroll
    for (int kc = 0; kc < 8; ++kc) {            // 8 chunks x 8 k4
        float4 a[8];
        #pragma unroll
        for (int u = 0; u < 8; ++u) a[u] = Arow[8 * kc + u];
        #pragma unroll
        for (int u = 0; u < 8; ++u) {
            const int k4 = 8 * kc + u;
            float4 b0  = Bs[(2 * tx + 0) * 64 + (k4 ^ keyB)];
            float4 b1v = Bs[(2 * tx + 1) * 64 + (k4 ^ keyB)];
            float4 w = W24[k4];
            acc0 = fmaf(fmaxf(a[u].x + b0.x, 0.f), w.x, acc0);
            acc0 = fmaf(fmaxf(a[u].y + b0.y, 0.f), w.y, acc0);
            acc0 = fmaf(fmaxf(a[u].z + b0.z, 0.f), w.z, acc0);
            acc0 = fmaf(fmaxf(a[u].w + b0.w, 0.f), w.w, acc0);
            acc1 = fmaf(fmaxf(a[u].x + b1v.x, 0.f), w.x, acc1);
            acc1 = fmaf(fmaxf(a[u].y + b1v.y, 0.f), w.y, acc1);
            acc1 = fmaf(fmaxf(a[u].z + b1v.z, 0.f), w.z, acc1);
            acc1 = fmaf(fmaxf(a[u].w + b1v.w, 0.f), w.w, acc1);
        }
    }

    const float bias2 = b2[0];
    const int i = i0 + ty;
    #pragma unroll
    for (int u = 0; u < 2; ++u) {
        int j = j0 + 2 * tx + u;
        float v = u ? acc1 : acc0;
        if (j > i) {
            int p = i * (2 * NF - i - 1) / 2 + (j - i - 1);
            out[p]             = (float)i;
            out[PAIRS + p]     = (float)j;
            out[2 * PAIRS + p] = v + bias2;
        }
    }
}

extern "C" void kernel_launch(void* const* d_in, const int* in_sizes, int n_in,
                              void* d_out, int out_size, void* d_ws, size_t ws_size,
                              hipStream_t stream) {
    const float* E  = (const float*)d_in[0];
    const float* W1 = (const float*)d_in[1];
    const float* b1 = (const float*)d_in[2];
    const float* W2 = (const float*)d_in[3];
    const float* b2 = (const float*)d_in[4];
    float* out = (float*)d_out;
    float* C   = (float*)d_ws;                  // 1 MiB

    gemm_mfma_kernel<<<dim3(16, 16), 256, 0, stream>>>(E, W1, b1, C);
    pair_kernel<<<272, 256, 0, stream>>>(C, W2, b2, out);
}

// Round 13
// 25.032 us; speedup vs baseline: 3.6035x; 3.6035x over previous
//
#include <hip/hip_runtime.h>

#define FD 768
#define HD 256
#define NF 512
#define NC 512
#define PAIRS (NF * (NF - 1) / 2)   // 130816

typedef __attribute__((ext_vector_type(4))) float f32x4;
typedef __attribute__((ext_vector_type(8))) short bf16x8;

// RNE float->bf16, packed pair (a = low 16, b = high 16)
__device__ inline unsigned bf16pk(float a, float b) {
    unsigned ua = __float_as_uint(a), ub = __float_as_uint(b);
    ua = (ua + 0x7FFFu + ((ua >> 16) & 1u)) >> 16;
    ub = (ub + 0x7FFFu + ((ub >> 16) & 1u)) >> 16;
    return ua | (ub << 16);
}

// ---------------------------------------------------------------------------
// Kernel 1 (EXACT R10 code — validated 3x, absmax 0.0156):
// C = E @ [W1top|W1bot] + [b1|0], bf16 MFMA, f32 accum. Grid 16x16, 32x32
// tile, 4 waves, K=768 in 3 rounds of 256. Coalesced f4 staging; XOR LDS.
// D layout: lane l, reg p -> C[r0+16wr+(l&15)][c0+16wc+4(l>>4)+p]
// ---------------------------------------------------------------------------
__global__ __launch_bounds__(256) void gemm_mfma_kernel(
    const float* __restrict__ E, const float* __restrict__ W1,
    const float* __restrict__ b1, float* __restrict__ C)
{
    __shared__ char lds[2 * 32 * 512];          // Et 16KB + Wt 16KB
    char* EtB = lds;
    char* WtB = lds + 32 * 512;

    const int tid  = threadIdx.x;
    const int r0   = blockIdx.y * 32, c0 = blockIdx.x * 32;
    const int c0w4 = (c0 & 255) >> 2;           // f4 col offset within W half
    const int dofs = (c0 >= 256) ? FD : 0;
    const int lane = tid & 63, wave = tid >> 6;
    const int wr = wave >> 1, wc = wave & 1;
    const int m = lane & 15, g = lane >> 4;
    const int arow = 16 * wc + m;               // Wt row (= local C col)
    const int brow = 16 * wr + m;               // Et row (= local C row)

    f32x4 acc = {0.f, 0.f, 0.f, 0.f};
    const float4* E4  = (const float4*)E;       // row pitch 192 f4
    const float4* W14 = (const float4*)W1;      // row pitch 64 f4

    for (int rnd = 0; rnd < 3; ++rnd) {
        if (rnd) __syncthreads();               // LDS reuse guard

        // ---- stage Et: 32 rows x 256 k, f4 loads + packed b64 writes ----
        #pragma unroll
        for (int s = 0; s < 8; ++s) {
            int idx = tid + s * 256;            // 2048 f4
            int r = idx >> 6, c4 = idx & 63;    // k = 4*c4
            float4 v = E4[(size_t)(r0 + r) * 192 + rnd * 64 + c4];
            uint2 pk;
            pk.x = bf16pk(v.x, v.y);
            pk.y = bf16pk(v.z, v.w);
            int gi = (c4 >> 1) ^ (r & 7);
            *(uint2*)(EtB + r * 512 + gi * 16 + (c4 & 1) * 8) = pk;
        }
        // ---- stage Wt: coalesced f4 loads + b32 scatter ----
        #pragma unroll
        for (int it2 = 0; it2 < 4; ++it2) {
            int task = it2 * 256 + tid;         // 1024 = 8 c-quads x 128 kp
            int c4 = task & 7, kp = task >> 3;
            int d = dofs + rnd * 256 + 2 * kp;
            float4 w0 = W14[(size_t)d * 64 + c0w4 + c4];
            float4 w1 = W14[(size_t)(d + 1) * 64 + c0w4 + c4];
            float a0v[4] = {w0.x, w0.y, w0.z, w0.w};
            float a1v[4] = {w1.x, w1.y, w1.z, w1.w};
            #pragma unroll
            for (int u = 0; u < 4; ++u) {
                int c = 4 * c4 + u;
                unsigned pk = bf16pk(a0v[u], a1v[u]);
                int gi = (kp >> 2) ^ (c & 7);
                *(unsigned*)(WtB + c * 512 + gi * 16 + (kp & 3) * 4) = pk;
            }
        }
        __syncthreads();

        // ---- 8 mfma per wave (K chunk = 256) ----
        #pragma unroll
        for (int ks = 0; ks < 8; ++ks) {
            int giA = (4 * ks + g) ^ (arow & 7);
            int giB = (4 * ks + g) ^ (brow & 7);
            bf16x8 af = *(const bf16x8*)(WtB + arow * 512 + giA * 16);
            bf16x8 bf = *(const bf16x8*)(EtB + brow * 512 + giB * 16);
            acc = __builtin_amdgcn_mfma_f32_16x16x32_bf16(af, bf, acc, 0, 0, 0);
        }
    }

    const int row = r0 + 16 * wr + m;           // n = l&15
    const int col = c0 + 16 * wc + 4 * g;       // m = 4*(l>>4)+p
    float4 b = {0.f, 0.f, 0.f, 0.f};
    if (c0 < 256) b = ((const float4*)b1)[col >> 2];
    float4 o = {acc[0] + b.x, acc[1] + b.y, acc[2] + b.z, acc[3] + b.w};
    *(float4*)&C[(size_t)row * NC + col] = o;
}

// ---------------------------------------------------------------------------
// Kernel 2: pair scores (EXACT R6 kernel-3 structure — validated at f32).
// 32x32 pair tile per block (136 triangular blocks, every CU <=1 block),
// 256 thr / 4 waves, 2x2 microtile: 4 ds_read_b128 per k4 for 4 pairs
// (1.0 LDS instr/pair). LDS f4[32][64] with XOR swizzle key (row>>1)&7.
// W2 via uniform global load (s_load). Same per-pair k-order as R10.
// ---------------------------------------------------------------------------
__global__ __launch_bounds__(256) void pair_kernel(
    const float* __restrict__ C, const float* __restrict__ W2,
    const float* __restrict__ b2, float* __restrict__ out)
{
    __shared__ float4 As[32 * 64];
    __shared__ float4 Bs[32 * 64];

    int rem = blockIdx.x, bi = 0;
    while (rem >= 16 - bi) { rem -= 16 - bi; ++bi; }
    const int bj = bi + rem;
    const int i0 = bi * 32, j0 = bj * 32;

    const int tid = threadIdx.x;
    const float4* C4 = (const float4*)C;        // row pitch 128 f4

    #pragma unroll
    for (int s = 0; s < 8; ++s) {
        int e = tid + 256 * s;
        int row = e >> 6, c4 = e & 63;
        int sc4 = c4 ^ ((row >> 1) & 7);
        As[row * 64 + sc4] = C4[(i0 + row) * 128 + c4];        // A half
        Bs[row * 64 + sc4] = C4[(j0 + row) * 128 + 64 + c4];   // B half
    }
    __syncthreads();

    const int tx = tid & 15, ty = tid >> 4;
    const int ka = ty & 7, kb = tx & 7;
    const float4* W24 = (const float4*)W2;      // uniform -> s_load

    float acc00 = 0.f, acc01 = 0.f, acc10 = 0.f, acc11 = 0.f;
    #pragma unroll 8
    for (int k4 = 0; k4 < HD / 4; ++k4) {
        float4 a0  = As[(2 * ty + 0) * 64 + (k4 ^ ka)];
        float4 a1  = As[(2 * ty + 1) * 64 + (k4 ^ ka)];
        float4 b0  = Bs[(2 * tx + 0) * 64 + (k4 ^ kb)];
        float4 b1v = Bs[(2 * tx + 1) * 64 + (k4 ^ kb)];
        float4 w = W24[k4];
        #define PACC(ACC, A, B) \
            ACC = fmaf(fmaxf(A.x + B.x, 0.f), w.x, ACC); \
            ACC = fmaf(fmaxf(A.y + B.y, 0.f), w.y, ACC); \
            ACC = fmaf(fmaxf(A.z + B.z, 0.f), w.z, ACC); \
            ACC = fmaf(fmaxf(A.w + B.w, 0.f), w.w, ACC);
        PACC(acc00, a0, b0) PACC(acc01, a0, b1v)
        PACC(acc10, a1, b0) PACC(acc11, a1, b1v)
        #undef PACC
    }

    const float bias2 = b2[0];
    #pragma unroll
    for (int u = 0; u < 4; ++u) {
        int i = i0 + 2 * ty + (u >> 1);
        int j = j0 + 2 * tx + (u & 1);
        float v = (u == 0) ? acc00 : (u == 1) ? acc01 : (u == 2) ? acc10 : acc11;
        if (j > i) {
            int p = i * (2 * NF - i - 1) / 2 + (j - i - 1);
            out[p]             = (float)i;
            out[PAIRS + p]     = (float)j;
            out[2 * PAIRS + p] = v + bias2;
        }
    }
}

extern "C" void kernel_launch(void* const* d_in, const int* in_sizes, int n_in,
                              void* d_out, int out_size, void* d_ws, size_t ws_size,
                              hipStream_t stream) {
    const float* E  = (const float*)d_in[0];
    const float* W1 = (const float*)d_in[1];
    const float* b1 = (const float*)d_in[2];
    const float* W2 = (const float*)d_in[3];
    const float* b2 = (const float*)d_in[4];
    float* out = (float*)d_out;
    float* C   = (float*)d_ws;                  // 1 MiB

    gemm_mfma_kernel<<<dim3(16, 16), 256, 0, stream>>>(E, W1, b1, C);
    pair_kernel<<<136, 256, 0, stream>>>(C, W2, b2, out);
}

// Round 14
// 23.656 us; speedup vs baseline: 3.8132x; 1.0582x over previous
//
#include <hip/hip_runtime.h>

#define FD 768
#define HD 256
#define NF 512
#define NC 512
#define PAIRS (NF * (NF - 1) / 2)   // 130816

typedef __attribute__((ext_vector_type(4))) float f32x4;
typedef __attribute__((ext_vector_type(8))) short bf16x8;

// RNE float->bf16, packed pair (a = low 16, b = high 16)
__device__ inline unsigned bf16pk(float a, float b) {
    unsigned ua = __float_as_uint(a), ub = __float_as_uint(b);
    ua = (ua + 0x7FFFu + ((ua >> 16) & 1u)) >> 16;
    ub = (ub + 0x7FFFu + ((ub >> 16) & 1u)) >> 16;
    return ua | (ub << 16);
}

// ---------------------------------------------------------------------------
// Kernel 1 (validated 4x, absmax 0.0156): C = E @ [W1top|W1bot] + [b1|0],
// bf16 MFMA, f32 accum. Grid 16x16, 32x32 tile, 4 waves, K=768 in 3 rounds
// of 256. Coalesced f4 staging for E and W; XOR-swizzled LDS.
// D layout: lane l, reg p -> C[r0+16wr+(l&15)][c0+16wc+4(l>>4)+p]
// ---------------------------------------------------------------------------
__global__ __launch_bounds__(256) void gemm_mfma_kernel(
    const float* __restrict__ E, const float* __restrict__ W1,
    const float* __restrict__ b1, float* __restrict__ C)
{
    __shared__ char lds[2 * 32 * 512];          // Et 16KB + Wt 16KB
    char* EtB = lds;
    char* WtB = lds + 32 * 512;

    const int tid  = threadIdx.x;
    const int r0   = blockIdx.y * 32, c0 = blockIdx.x * 32;
    const int c0w4 = (c0 & 255) >> 2;           // f4 col offset within W half
    const int dofs = (c0 >= 256) ? FD : 0;
    const int lane = tid & 63, wave = tid >> 6;
    const int wr = wave >> 1, wc = wave & 1;
    const int m = lane & 15, g = lane >> 4;
    const int arow = 16 * wc + m;               // Wt row (= local C col)
    const int brow = 16 * wr + m;               // Et row (= local C row)

    f32x4 acc = {0.f, 0.f, 0.f, 0.f};
    const float4* E4  = (const float4*)E;       // row pitch 192 f4
    const float4* W14 = (const float4*)W1;      // row pitch 64 f4

    for (int rnd = 0; rnd < 3; ++rnd) {
        if (rnd) __syncthreads();               // LDS reuse guard

        // ---- stage Et: 32 rows x 256 k, f4 loads + packed b64 writes ----
        #pragma unroll
        for (int s = 0; s < 8; ++s) {
            int idx = tid + s * 256;            // 2048 f4
            int r = idx >> 6, c4 = idx & 63;    // k = 4*c4
            float4 v = E4[(size_t)(r0 + r) * 192 + rnd * 64 + c4];
            uint2 pk;
            pk.x = bf16pk(v.x, v.y);
            pk.y = bf16pk(v.z, v.w);
            int gi = (c4 >> 1) ^ (r & 7);
            *(uint2*)(EtB + r * 512 + gi * 16 + (c4 & 1) * 8) = pk;
        }
        // ---- stage Wt: coalesced f4 loads + b32 scatter ----
        #pragma unroll
        for (int it2 = 0; it2 < 4; ++it2) {
            int task = it2 * 256 + tid;         // 1024 = 8 c-quads x 128 kp
            int c4 = task & 7, kp = task >> 3;
            int d = dofs + rnd * 256 + 2 * kp;
            float4 w0 = W14[(size_t)d * 64 + c0w4 + c4];
            float4 w1 = W14[(size_t)(d + 1) * 64 + c0w4 + c4];
            float a0v[4] = {w0.x, w0.y, w0.z, w0.w};
            float a1v[4] = {w1.x, w1.y, w1.z, w1.w};
            #pragma unroll
            for (int u = 0; u < 4; ++u) {
                int c = 4 * c4 + u;
                unsigned pk = bf16pk(a0v[u], a1v[u]);
                int gi = (kp >> 2) ^ (c & 7);
                *(unsigned*)(WtB + c * 512 + gi * 16 + (kp & 3) * 4) = pk;
            }
        }
        __syncthreads();

        // ---- 8 mfma per wave (K chunk = 256) ----
        #pragma unroll
        for (int ks = 0; ks < 8; ++ks) {
            int giA = (4 * ks + g) ^ (arow & 7);
            int giB = (4 * ks + g) ^ (brow & 7);
            bf16x8 af = *(const bf16x8*)(WtB + arow * 512 + giA * 16);
            bf16x8 bf = *(const bf16x8*)(EtB + brow * 512 + giB * 16);
            acc = __builtin_amdgcn_mfma_f32_16x16x32_bf16(af, bf, acc, 0, 0, 0);
        }
    }

    const int row = r0 + 16 * wr + m;           // n = l&15
    const int col = c0 + 16 * wc + 4 * g;       // m = 4*(l>>4)+p
    float4 b = {0.f, 0.f, 0.f, 0.f};
    if (c0 < 256) b = ((const float4*)b1)[col >> 2];
    float4 o = {acc[0] + b.x, acc[1] + b.y, acc[2] + b.z, acc[3] + b.w};
    *(float4*)&C[(size_t)row * NC + col] = o;
}

// ---------------------------------------------------------------------------
// Kernel 2: pair scores (validated 3x at absmax 0.0156 — best config).
// 16x32 tile, 272 blocks, 256 thr / 4 waves, 1x2 micro. XOR-swizzled LDS
// (A: broadcast reads; B: 16 addrs 2/quad = free). W2 via uniform s_load.
// ---------------------------------------------------------------------------
__global__ __launch_bounds__(256) void pair_kernel(
    const float* __restrict__ C, const float* __restrict__ W2,
    const float* __restrict__ b2, float* __restrict__ out)
{
    __shared__ float4 As[16 * 64];
    __shared__ float4 Bs[32 * 64];

    int rem = blockIdx.x, bi = 0;
    while (rem >= 16 - (bi >> 1)) { rem -= 16 - (bi >> 1); ++bi; }
    const int bj = (bi >> 1) + rem;
    const int i0 = bi * 16, j0 = bj * 32;

    const int tid = threadIdx.x;
    const float4* C4 = (const float4*)C;        // row pitch 128 f4

    #pragma unroll
    for (int s = 0; s < 4; ++s) {               // A: 16 rows x 64 f4
        int idx = tid + 256 * s;
        int row = idx >> 6, c4 = idx & 63;
        As[row * 64 + (c4 ^ ((row >> 1) & 7))] = C4[(i0 + row) * 128 + c4];
    }
    #pragma unroll
    for (int s = 0; s < 8; ++s) {               // B: 32 rows x 64 f4
        int idx = tid + 256 * s;
        int row = idx >> 6, c4 = idx & 63;
        Bs[row * 64 + (c4 ^ ((row >> 1) & 7))] = C4[(j0 + row) * 128 + 64 + c4];
    }
    __syncthreads();

    const int tx = tid & 15, ty = tid >> 4;
    const int keyA = (ty >> 1) & 7, keyB = tx & 7;
    const float4* W24 = (const float4*)W2;

    float acc0 = 0.f, acc1 = 0.f;
    #pragma unroll 8
    for (int k4 = 0; k4 < HD / 4; ++k4) {
        float4 a   = As[ty * 64 + (k4 ^ keyA)];
        float4 b0  = Bs[(2 * tx + 0) * 64 + (k4 ^ keyB)];
        float4 b1v = Bs[(2 * tx + 1) * 64 + (k4 ^ keyB)];
        float4 w = W24[k4];                     // uniform -> s_load
        acc0 = fmaf(fmaxf(a.x + b0.x, 0.f), w.x, acc0);
        acc0 = fmaf(fmaxf(a.y + b0.y, 0.f), w.y, acc0);
        acc0 = fmaf(fmaxf(a.z + b0.z, 0.f), w.z, acc0);
        acc0 = fmaf(fmaxf(a.w + b0.w, 0.f), w.w, acc0);
        acc1 = fmaf(fmaxf(a.x + b1v.x, 0.f), w.x, acc1);
        acc1 = fmaf(fmaxf(a.y + b1v.y, 0.f), w.y, acc1);
        acc1 = fmaf(fmaxf(a.z + b1v.z, 0.f), w.z, acc1);
        acc1 = fmaf(fmaxf(a.w + b1v.w, 0.f), w.w, acc1);
    }

    const float bias2 = b2[0];
    const int i = i0 + ty;
    #pragma unroll
    for (int u = 0; u < 2; ++u) {
        int j = j0 + 2 * tx + u;
        float v = u ? acc1 : acc0;
        if (j > i) {
            int p = i * (2 * NF - i - 1) / 2 + (j - i - 1);
            out[p]             = (float)i;
            out[PAIRS + p]     = (float)j;
            out[2 * PAIRS + p] = v + bias2;
        }
    }
}

extern "C" void kernel_launch(void* const* d_in, const int* in_sizes, int n_in,
                              void* d_out, int out_size, void* d_ws, size_t ws_size,
                              hipStream_t stream) {
    const float* E  = (const float*)d_in[0];
    const float* W1 = (const float*)d_in[1];
    const float* b1 = (const float*)d_in[2];
    const float* W2 = (const float*)d_in[3];
    const float* b2 = (const float*)d_in[4];
    float* out = (float*)d_out;
    float* C   = (float*)d_ws;                  // 1 MiB

    gemm_mfma_kernel<<<dim3(16, 16), 256, 0, stream>>>(E, W1, b1, C);
    pair_kernel<<<272, 256, 0, stream>>>(C, W2, b2, out);
}

// Round 15
// 23.569 us; speedup vs baseline: 3.8273x; 1.0037x over previous
//
#include <hip/hip_runtime.h>

#define FD 768
#define HD 256
#define NF 512
#define NC 512
#define PAIRS (NF * (NF - 1) / 2)   // 130816

typedef __attribute__((ext_vector_type(4))) float f32x4;
typedef __attribute__((ext_vector_type(8))) short bf16x8;

// RNE float->bf16, packed pair (a = low 16, b = high 16)
__device__ inline unsigned bf16pk(float a, float b) {
    unsigned ua = __float_as_uint(a), ub = __float_as_uint(b);
    ua = (ua + 0x7FFFu + ((ua >> 16) & 1u)) >> 16;
    ub = (ub + 0x7FFFu + ((ub >> 16) & 1u)) >> 16;
    return ua | (ub << 16);
}

// unpack bf16 pair (packed [hi:lo]) to two f32 (exact: bf16 = truncated f32)
__device__ inline void bfup(unsigned u, float& lo, float& hi) {
    lo = __uint_as_float(u << 16);
    hi = __uint_as_float(u & 0xFFFF0000u);
}

// ---------------------------------------------------------------------------
// Kernel 1 (R14 structure, validated 5x — ONLY epilogue changed to bf16 store)
// Cbf = bf16( E @ [W1top|W1bot] + [b1|0] ). Grid 16x16, 32x32 tile, 4 waves,
// K=768 in 3 rounds of 256; coalesced f4 staging; XOR-swizzled LDS.
// D layout: lane l, reg p -> C[r0+16wr+(l&15)][c0+16wc+4(l>>4)+p]
// ---------------------------------------------------------------------------
__global__ __launch_bounds__(256) void gemm_mfma_kernel(
    const float* __restrict__ E, const float* __restrict__ W1,
    const float* __restrict__ b1, ushort* __restrict__ Cbf)
{
    __shared__ char lds[2 * 32 * 512];          // Et 16KB + Wt 16KB
    char* EtB = lds;
    char* WtB = lds + 32 * 512;

    const int tid  = threadIdx.x;
    const int r0   = blockIdx.y * 32, c0 = blockIdx.x * 32;
    const int c0w4 = (c0 & 255) >> 2;           // f4 col offset within W half
    const int dofs = (c0 >= 256) ? FD : 0;
    const int lane = tid & 63, wave = tid >> 6;
    const int wr = wave >> 1, wc = wave & 1;
    const int m = lane & 15, g = lane >> 4;
    const int arow = 16 * wc + m;               // Wt row (= local C col)
    const int brow = 16 * wr + m;               // Et row (= local C row)

    f32x4 acc = {0.f, 0.f, 0.f, 0.f};
    const float4* E4  = (const float4*)E;       // row pitch 192 f4
    const float4* W14 = (const float4*)W1;      // row pitch 64 f4

    for (int rnd = 0; rnd < 3; ++rnd) {
        if (rnd) __syncthreads();               // LDS reuse guard

        // ---- stage Et: 32 rows x 256 k, f4 loads + packed b64 writes ----
        #pragma unroll
        for (int s = 0; s < 8; ++s) {
            int idx = tid + s * 256;            // 2048 f4
            int r = idx >> 6, c4 = idx & 63;    // k = 4*c4
            float4 v = E4[(size_t)(r0 + r) * 192 + rnd * 64 + c4];
            uint2 pk;
            pk.x = bf16pk(v.x, v.y);
            pk.y = bf16pk(v.z, v.w);
            int gi = (c4 >> 1) ^ (r & 7);
            *(uint2*)(EtB + r * 512 + gi * 16 + (c4 & 1) * 8) = pk;
        }
        // ---- stage Wt: coalesced f4 loads + b32 scatter ----
        #pragma unroll
        for (int it2 = 0; it2 < 4; ++it2) {
            int task = it2 * 256 + tid;         // 1024 = 8 c-quads x 128 kp
            int c4 = task & 7, kp = task >> 3;
            int d = dofs + rnd * 256 + 2 * kp;
            float4 w0 = W14[(size_t)d * 64 + c0w4 + c4];
            float4 w1 = W14[(size_t)(d + 1) * 64 + c0w4 + c4];
            float a0v[4] = {w0.x, w0.y, w0.z, w0.w};
            float a1v[4] = {w1.x, w1.y, w1.z, w1.w};
            #pragma unroll
            for (int u = 0; u < 4; ++u) {
                int c = 4 * c4 + u;
                unsigned pk = bf16pk(a0v[u], a1v[u]);
                int gi = (kp >> 2) ^ (c & 7);
                *(unsigned*)(WtB + c * 512 + gi * 16 + (kp & 3) * 4) = pk;
            }
        }
        __syncthreads();

        // ---- 8 mfma per wave (K chunk = 256) ----
        #pragma unroll
        for (int ks = 0; ks < 8; ++ks) {
            int giA = (4 * ks + g) ^ (arow & 7);
            int giB = (4 * ks + g) ^ (brow & 7);
            bf16x8 af = *(const bf16x8*)(WtB + arow * 512 + giA * 16);
            bf16x8 bf = *(const bf16x8*)(EtB + brow * 512 + giB * 16);
            acc = __builtin_amdgcn_mfma_f32_16x16x32_bf16(af, bf, acc, 0, 0, 0);
        }
    }

    const int row = r0 + 16 * wr + m;           // n = l&15
    const int col = c0 + 16 * wc + 4 * g;       // m = 4*(l>>4)+p
    float4 b = {0.f, 0.f, 0.f, 0.f};
    if (c0 < 256) b = ((const float4*)b1)[col >> 2];
    uint2 pk;
    pk.x = bf16pk(acc[0] + b.x, acc[1] + b.y);
    pk.y = bf16pk(acc[2] + b.z, acc[3] + b.w);
    *(uint2*)&Cbf[(size_t)row * NC + col] = pk; // 8B aligned (col % 4 == 0)
}

// ---------------------------------------------------------------------------
// Kernel 2: pair scores from bf16 C. Same validated structure as R14
// (16x32 tile, 272 blocks, 256 thr / 4 waves, 1x2 micro), but each
// ds_read_b128 now carries 8 k-values -> LDS instrs halved (96/wave),
// staging halved (24KB/block). XOR key (row>>1)&7: a-reads broadcast,
// b-reads 16 addrs / 8 quads = 2-way = free. W2 via uniform s_load.
// ---------------------------------------------------------------------------
__global__ __launch_bounds__(256) void pair_kernel(
    const ushort* __restrict__ Cbf, const float* __restrict__ W2,
    const float* __restrict__ b2, float* __restrict__ out)
{
    __shared__ uint4 As[16 * 32];   // 8KB:  [row][k8] A-half (256 bf16/row)
    __shared__ uint4 Bs[32 * 32];   // 16KB: [row][k8] B-half

    int rem = blockIdx.x, bi = 0;
    while (rem >= 16 - (bi >> 1)) { rem -= 16 - (bi >> 1); ++bi; }
    const int bj = (bi >> 1) + rem;
    const int i0 = bi * 16, j0 = bj * 32;

    const int tid = threadIdx.x;

    #pragma unroll
    for (int s = 0; s < 2; ++s) {               // A: 16 rows x 32 u4
        int idx = tid + 256 * s;
        int row = idx >> 5, g = idx & 31;
        const uint4* src = (const uint4*)(Cbf + (size_t)(i0 + row) * NC);
        As[row * 32 + (g ^ ((row >> 1) & 7))] = src[g];
    }
    #pragma unroll
    for (int s = 0; s < 4; ++s) {               // B: 32 rows x 32 u4
        int idx = tid + 256 * s;
        int row = idx >> 5, g = idx & 31;
        const uint4* src = (const uint4*)(Cbf + (size_t)(j0 + row) * NC + HD);
        Bs[row * 32 + (g ^ ((row >> 1) & 7))] = src[g];
    }
    __syncthreads();

    const int tx = tid & 15, ty = tid >> 4;
    const int keyA = (ty >> 1) & 7, keyB = tx & 7;  // b rows 2tx,2tx+1 share key
    const float4* W24 = (const float4*)W2;          // uniform -> s_load

    float acc0 = 0.f, acc1 = 0.f;
    #pragma unroll 4
    for (int k8 = 0; k8 < 32; ++k8) {           // 8 k per iteration
        uint4 av  = As[ty * 32 + (k8 ^ keyA)];
        uint4 bv0 = Bs[(2 * tx + 0) * 32 + (k8 ^ keyB)];
        uint4 bv1 = Bs[(2 * tx + 1) * 32 + (k8 ^ keyB)];
        float4 wlo = W24[2 * k8], whi = W24[2 * k8 + 1];
        const float wv[8] = {wlo.x, wlo.y, wlo.z, wlo.w, whi.x, whi.y, whi.z, whi.w};
        unsigned au[4] = {av.x, av.y, av.z, av.w};
        unsigned b0u[4] = {bv0.x, bv0.y, bv0.z, bv0.w};
        unsigned b1u[4] = {bv1.x, bv1.y, bv1.z, bv1.w};
        #pragma unroll
        for (int q = 0; q < 4; ++q) {
            float a_lo, a_hi, p_lo, p_hi;
            bfup(au[q], a_lo, a_hi);
            bfup(b0u[q], p_lo, p_hi);
            acc0 = fmaf(fmaxf(a_lo + p_lo, 0.f), wv[2 * q + 0], acc0);
            acc0 = fmaf(fmaxf(a_hi + p_hi, 0.f), wv[2 * q + 1], acc0);
            bfup(b1u[q], p_lo, p_hi);
            acc1 = fmaf(fmaxf(a_lo + p_lo, 0.f), wv[2 * q + 0], acc1);
            acc1 = fmaf(fmaxf(a_hi + p_hi, 0.f), wv[2 * q + 1], acc1);
        }
    }

    const float bias2 = b2[0];
    const int i = i0 + ty;
    #pragma unroll
    for (int u = 0; u < 2; ++u) {
        int j = j0 + 2 * tx + u;
        float v = u ? acc1 : acc0;
        if (j > i) {
            int p = i * (2 * NF - i - 1) / 2 + (j - i - 1);
            out[p]             = (float)i;
            out[PAIRS + p]     = (float)j;
            out[2 * PAIRS + p] = v + bias2;
        }
    }
}

extern "C" void kernel_launch(void* const* d_in, const int* in_sizes, int n_in,
                              void* d_out, int out_size, void* d_ws, size_t ws_size,
                              hipStream_t stream) {
    const float* E  = (const float*)d_in[0];
    const float* W1 = (const float*)d_in[1];
    const float* b1 = (const float*)d_in[2];
    const float* W2 = (const float*)d_in[3];
    const float* b2 = (const float*)d_in[4];
    float* out  = (float*)d_out;
    ushort* Cbf = (ushort*)d_ws;                // 512 KiB bf16 C

    gemm_mfma_kernel<<<dim3(16, 16), 256, 0, stream>>>(E, W1, b1, Cbf);
    pair_kernel<<<272, 256, 0, stream>>>(Cbf, W2, b2, out);
}